// Round 1
// baseline (3831.602 us; speedup 1.0000x reference)
//
#include <hip/hip_runtime.h>
#include <hip/hip_bf16.h>

// MPNN on MI355X.
// Factorization: msg[e,o] = sum_k t[e,k]*Q[src,k,o] + q0[src,o],
// Q'[n] = h[n] @ W2ext  (W2ext[i][k*32+o] = en_W2[k][i*32+o], col block 1024..1055 = b2)
// Q' stored bf16 [N,1056] (211MB, L3-resident). Fallback path (small ws) recomputes per edge.

#define NN 100000
#define NE 320000
#define DD 32
#define QC 1056   // 33*32 (32 k-rows + 1 bias row)

__device__ __forceinline__ float bf2f(unsigned short u) {
    return __uint_as_float(((unsigned int)u) << 16);
}
__device__ __forceinline__ unsigned short f2bf(float f) {
    unsigned int x = __float_as_uint(f);
    unsigned int r = (x + 0x7fffu + ((x >> 16) & 1u)) >> 16;
    return (unsigned short)r;
}

// ---- build W2ext [32][1056]: W2ext[i*1056 + k*32+o] = W2[k*1024 + i*32 + o]; bias block = b2
__global__ __launch_bounds__(256) void k_w2ext(const float* __restrict__ W2,
                                               const float* __restrict__ b2,
                                               float* __restrict__ W2ext) {
    int idx = blockIdx.x * 256 + threadIdx.x;
    if (idx >= 32 * QC) return;
    int i = idx / QC, c = idx % QC;
    float v;
    if (c < 1024) { int k = c >> 5, o = c & 31; v = W2[k * 1024 + i * 32 + o]; }
    else          { v = b2[i * 32 + (c - 1024)]; }
    W2ext[idx] = v;
}

// ---- node encoder + projection: h = relu(relu(relu(emb[nt]) @ encW + encB) @ projW + projB)
__global__ __launch_bounds__(256) void k_node_enc(
    const int* __restrict__ nfeats, const float* __restrict__ emb,
    const float* __restrict__ encW, const float* __restrict__ encB,
    const float* __restrict__ projW, const float* __restrict__ projB,
    float* __restrict__ h) {
    __shared__ float sEncW[1024], sProjW[1024], sEncB[32], sProjB[32];
    __shared__ float sEmb[8][33], sNh[8][33];
    int tid = threadIdx.x;
    for (int i = tid; i < 1024; i += 256) { sEncW[i] = encW[i]; sProjW[i] = projW[i]; }
    if (tid < 32) { sEncB[tid] = encB[tid]; sProjB[tid] = projB[tid]; }
    int ln = tid >> 5, o = tid & 31;
    int node = blockIdx.x * 8 + ln;
    int nt = nfeats[node];
    sEmb[ln][o] = fmaxf(emb[nt * DD + o], 0.f);
    __syncthreads();
    float acc = sEncB[o];
    #pragma unroll
    for (int i = 0; i < 32; ++i) acc += sEmb[ln][i] * sEncW[i * 32 + o];
    sNh[ln][o] = fmaxf(acc, 0.f);
    __syncthreads();
    float acc2 = sProjB[o];
    #pragma unroll
    for (int i = 0; i < 32; ++i) acc2 += sNh[ln][i] * sProjW[i * 32 + o];
    h[node * DD + o] = fmaxf(acc2, 0.f);
}

// ---- edge encoder: t = relu((efeats @ eencW + eencB) @ enW1 + enB1)
__global__ __launch_bounds__(256) void k_edge_t(
    const float* __restrict__ efeats,
    const float* __restrict__ eencW, const float* __restrict__ eencB,
    const float* __restrict__ enW1, const float* __restrict__ enB1,
    float* __restrict__ t) {
    __shared__ float sEW[512], sW1[1024], sEB[32], sB1[32];
    __shared__ float sEf[8][17], sEh[8][33];
    int tid = threadIdx.x;
    for (int i = tid; i < 512; i += 256) sEW[i] = eencW[i];
    for (int i = tid; i < 1024; i += 256) sW1[i] = enW1[i];
    if (tid < 32) { sEB[tid] = eencB[tid]; sB1[tid] = enB1[tid]; }
    int ln = tid >> 5, o = tid & 31;
    int e = blockIdx.x * 8 + ln;
    if (o < 16) sEf[ln][o] = efeats[e * 16 + o];
    __syncthreads();
    float acc = sEB[o];
    #pragma unroll
    for (int i = 0; i < 16; ++i) acc += sEf[ln][i] * sEW[i * 32 + o];
    sEh[ln][o] = acc;   // no relu on eh
    __syncthreads();
    float acc2 = sB1[o];
    #pragma unroll
    for (int i = 0; i < 32; ++i) acc2 += sEh[ln][i] * sW1[i * 32 + o];
    t[e * 32 + o] = fmaxf(acc2, 0.f);
}

// ---- per-step: Q'[n,c] = sum_i h[n,i] * W2ext[i*1056+c]  (bf16 out)
// block: 32 nodes; thread (m = tid>>3, l8 = tid&7) handles cols l8*4 + 32*cg
__global__ __launch_bounds__(256) void k_Q(
    const float* __restrict__ h, const float* __restrict__ W2ext,
    unsigned short* __restrict__ Q) {
    int tid = threadIdx.x;
    int n0 = blockIdx.x * 32;
    int m = tid >> 3, l8 = tid & 7;
    const float* hp = h + (long)(n0 + m) * 32;
    float hr[32];
    #pragma unroll
    for (int i4 = 0; i4 < 8; ++i4) {
        float4 hv = *(const float4*)(hp + i4 * 4);
        hr[4 * i4] = hv.x; hr[4 * i4 + 1] = hv.y; hr[4 * i4 + 2] = hv.z; hr[4 * i4 + 3] = hv.w;
    }
    for (int cg = 0; cg < 33; ++cg) {
        int c = cg * 32 + l8 * 4;
        float a0 = 0.f, a1 = 0.f, a2 = 0.f, a3 = 0.f;
        #pragma unroll 8
        for (int i = 0; i < 32; ++i) {
            float4 w = *(const float4*)(W2ext + i * QC + c);
            float hi = hr[i];
            a0 += hi * w.x; a1 += hi * w.y; a2 += hi * w.z; a3 += hi * w.w;
        }
        ushort4 qv;
        qv.x = f2bf(a0); qv.y = f2bf(a1); qv.z = f2bf(a2); qv.w = f2bf(a3);
        *(ushort4*)(Q + (long)(n0 + m) * QC + c) = qv;
    }
}

// ---- msg + scatter (Q path): block = 32 edges, 8 lanes/edge, 4 cols/lane
__global__ __launch_bounds__(256) void k_msgQ(
    const float* __restrict__ t, const int* __restrict__ src, const int* __restrict__ dst,
    const unsigned short* __restrict__ Q, float* __restrict__ agg) {
    __shared__ float sT[32][33];
    __shared__ int sSrc[32], sDst[32];
    int tid = threadIdx.x;
    int e0 = blockIdx.x * 32;
    if (tid < 32) sSrc[tid] = src[e0 + tid];
    else if (tid < 64) sDst[tid - 32] = dst[e0 + tid - 32];
    for (int idx = tid; idx < 1024; idx += 256) {
        int el = idx >> 5, k = idx & 31;
        sT[el][k] = t[(e0 + el) * 32 + k];
    }
    __syncthreads();
    int el = tid >> 3, l8 = tid & 7;
    const unsigned short* qp = Q + (long)sSrc[el] * QC + l8 * 4;
    float a0 = 0.f, a1 = 0.f, a2 = 0.f, a3 = 0.f;
    #pragma unroll 8
    for (int k = 0; k < 32; ++k) {
        float tk = sT[el][k];
        ushort4 q = *(const ushort4*)(qp + k * 32);
        a0 += tk * bf2f(q.x); a1 += tk * bf2f(q.y); a2 += tk * bf2f(q.z); a3 += tk * bf2f(q.w);
    }
    ushort4 qb = *(const ushort4*)(qp + 1024);
    a0 += bf2f(qb.x); a1 += bf2f(qb.y); a2 += bf2f(qb.z); a3 += bf2f(qb.w);
    float* ap = agg + (long)sDst[el] * 32 + l8 * 4;
    atomicAdd(ap + 0, a0); atomicAdd(ap + 1, a1);
    atomicAdd(ap + 2, a2); atomicAdd(ap + 3, a3);
}

// ---- msg + scatter (fallback, no Q buffer): recompute We per edge from t and W2ext
__global__ __launch_bounds__(256) void k_msgC(
    const float* __restrict__ t, const int* __restrict__ src, const int* __restrict__ dst,
    const float* __restrict__ h, const float* __restrict__ W2ext, float* __restrict__ agg) {
    __shared__ float sT[32][33], sH[32][33];
    __shared__ int sSrc[32], sDst[32];
    int tid = threadIdx.x;
    int e0 = blockIdx.x * 32;
    if (tid < 32) sSrc[tid] = src[e0 + tid];
    else if (tid < 64) sDst[tid - 32] = dst[e0 + tid - 32];
    __syncthreads();
    for (int idx = tid; idx < 1024; idx += 256) {
        int el = idx >> 5, k = idx & 31;
        sT[el][k] = t[(e0 + el) * 32 + k];
        sH[el][k] = h[(long)sSrc[el] * 32 + k];
    }
    __syncthreads();
    int el = tid >> 3, l8 = tid & 7;
    int c0 = l8 * 4;
    float m0 = 0.f, m1 = 0.f, m2 = 0.f, m3 = 0.f;
    for (int i = 0; i < 32; ++i) {
        const float* wrow = W2ext + i * QC;
        float4 wb = *(const float4*)(wrow + 1024 + c0);
        float w0 = wb.x, w1 = wb.y, w2 = wb.z, w3 = wb.w;
        #pragma unroll 8
        for (int k = 0; k < 32; ++k) {
            float tk = sT[el][k];
            float4 w = *(const float4*)(wrow + k * 32 + c0);
            w0 += tk * w.x; w1 += tk * w.y; w2 += tk * w.z; w3 += tk * w.w;
        }
        float hi = sH[el][i];
        m0 += hi * w0; m1 += hi * w1; m2 += hi * w2; m3 += hi * w3;
    }
    float* ap = agg + (long)sDst[el] * 32 + c0;
    atomicAdd(ap + 0, m0); atomicAdd(ap + 1, m1);
    atomicAdd(ap + 2, m2); atomicAdd(ap + 3, m3);
}

// ---- GRU step (in-place h update): x = relu(agg + conv_b)
__global__ __launch_bounds__(256) void k_gru(
    const float* __restrict__ agg, const float* __restrict__ convB,
    const float* __restrict__ Wi, const float* __restrict__ Wh,
    const float* __restrict__ bi, const float* __restrict__ bh,
    float* __restrict__ h) {
    __shared__ float sWi[3072], sWh[3072], sBi[96], sBh[96], sCb[32];
    __shared__ float sX[8][33], sH[8][33];
    int tid = threadIdx.x;
    for (int i = tid; i < 3072; i += 256) { sWi[i] = Wi[i]; sWh[i] = Wh[i]; }
    if (tid < 96) { sBi[tid] = bi[tid]; sBh[tid] = bh[tid]; }
    if (tid < 32) sCb[tid] = convB[tid];
    int ln = tid >> 5, o = tid & 31;
    int node = blockIdx.x * 8 + ln;
    float hv = h[node * 32 + o];
    float av = agg[node * 32 + o];
    __syncthreads();
    sX[ln][o] = fmaxf(av + sCb[o], 0.f);
    sH[ln][o] = hv;
    __syncthreads();
    float air = sBi[o], aiz = sBi[o + 32], ain = sBi[o + 64];
    float ahr = sBh[o], ahz = sBh[o + 32], ahn = sBh[o + 64];
    #pragma unroll 8
    for (int i = 0; i < 32; ++i) {
        float x = sX[ln][i], hh = sH[ln][i];
        air += x * sWi[i * 96 + o];      ahr += hh * sWh[i * 96 + o];
        aiz += x * sWi[i * 96 + o + 32]; ahz += hh * sWh[i * 96 + o + 32];
        ain += x * sWi[i * 96 + o + 64]; ahn += hh * sWh[i * 96 + o + 64];
    }
    float r = 1.f / (1.f + __expf(-(air + ahr)));
    float z = 1.f / (1.f + __expf(-(aiz + ahz)));
    float ng = tanhf(ain + r * ahn);
    h[node * 32 + o] = (1.f - z) * ng + z * hv;
}

// ---- decoder: 3x (linear+prelu) + final 32x3
__global__ __launch_bounds__(256) void k_dec(
    const float* __restrict__ h,
    const float* __restrict__ W1, const float* __restrict__ b1, const float* __restrict__ a1,
    const float* __restrict__ W2, const float* __restrict__ b2, const float* __restrict__ a2,
    const float* __restrict__ W3, const float* __restrict__ b3, const float* __restrict__ a3,
    const float* __restrict__ W4, const float* __restrict__ b4,
    float* __restrict__ out) {
    __shared__ float sW1[1024], sW2[1024], sW3[1024], sW4[96];
    __shared__ float sB1[32], sB2[32], sB3[32], sB4[3];
    __shared__ float sYa[8][33], sYb[8][33];
    int tid = threadIdx.x;
    for (int i = tid; i < 1024; i += 256) { sW1[i] = W1[i]; sW2[i] = W2[i]; sW3[i] = W3[i]; }
    if (tid < 96) sW4[tid] = W4[tid];
    if (tid < 32) { sB1[tid] = b1[tid]; sB2[tid] = b2[tid]; sB3[tid] = b3[tid]; }
    if (tid < 3) sB4[tid] = b4[tid];
    float A1 = a1[0], A2 = a2[0], A3 = a3[0];
    int ln = tid >> 5, o = tid & 31;
    int node = blockIdx.x * 8 + ln;
    sYa[ln][o] = h[node * 32 + o];
    __syncthreads();
    float acc = sB1[o];
    #pragma unroll
    for (int i = 0; i < 32; ++i) acc += sYa[ln][i] * sW1[i * 32 + o];
    acc = acc >= 0.f ? acc : A1 * acc;
    sYb[ln][o] = acc;
    __syncthreads();
    acc = sB2[o];
    #pragma unroll
    for (int i = 0; i < 32; ++i) acc += sYb[ln][i] * sW2[i * 32 + o];
    acc = acc >= 0.f ? acc : A2 * acc;
    __syncthreads();   // everyone done reading sYa
    sYa[ln][o] = acc;
    __syncthreads();
    acc = sB3[o];
    #pragma unroll
    for (int i = 0; i < 32; ++i) acc += sYa[ln][i] * sW3[i * 32 + o];
    acc = acc >= 0.f ? acc : A3 * acc;
    __syncthreads();
    sYb[ln][o] = acc;
    __syncthreads();
    if (o < 3) {
        float r = sB4[o];
        #pragma unroll
        for (int i = 0; i < 32; ++i) r += sYb[ln][i] * sW4[i * 3 + o];
        out[node * 3 + o] = r;
    }
}

extern "C" void kernel_launch(void* const* d_in, const int* in_sizes, int n_in,
                              void* d_out, int out_size, void* d_ws, size_t ws_size,
                              hipStream_t stream) {
    const int*   nfeats = (const int*)d_in[0];
    const float* efeats = (const float*)d_in[1];
    const int*   src    = (const int*)d_in[2];
    const int*   dst    = (const int*)d_in[3];
    const float* emb    = (const float*)d_in[4];
    const float* encW   = (const float*)d_in[5];
    const float* encB   = (const float*)d_in[6];
    const float* eencW  = (const float*)d_in[7];
    const float* eencB  = (const float*)d_in[8];
    const float* projW  = (const float*)d_in[9];
    const float* projB  = (const float*)d_in[10];
    const float* enW1   = (const float*)d_in[11];
    const float* enB1   = (const float*)d_in[12];
    const float* enW2   = (const float*)d_in[13];
    const float* enB2   = (const float*)d_in[14];
    const float* convB  = (const float*)d_in[15];
    const float* gruWi  = (const float*)d_in[16];
    const float* gruWh  = (const float*)d_in[17];
    const float* gruBi  = (const float*)d_in[18];
    const float* gruBh  = (const float*)d_in[19];
    const float* dW1 = (const float*)d_in[20]; const float* db1 = (const float*)d_in[21]; const float* da1 = (const float*)d_in[22];
    const float* dW2 = (const float*)d_in[23]; const float* db2 = (const float*)d_in[24]; const float* da2 = (const float*)d_in[25];
    const float* dW3 = (const float*)d_in[26]; const float* db3 = (const float*)d_in[27]; const float* da3 = (const float*)d_in[28];
    const float* dW4 = (const float*)d_in[29]; const float* db4 = (const float*)d_in[30];
    float* out = (float*)d_out;

    float* h     = (float*)d_ws;                 // NN*32
    float* t     = h + (size_t)NN * 32;          // NE*32
    float* agg   = t + (size_t)NE * 32;          // NN*32
    float* W2ext = agg + (size_t)NN * 32;        // 32*QC
    unsigned short* Q = (unsigned short*)(W2ext + 32 * QC);  // NN*QC bf16

    size_t need_base = ((size_t)NN * 32 + (size_t)NE * 32 + (size_t)NN * 32 + 32 * QC) * 4;
    size_t need_q    = need_base + (size_t)NN * QC * 2;
    bool useQ = (ws_size >= need_q);

    k_w2ext<<<(32 * QC + 255) / 256, 256, 0, stream>>>(enW2, enB2, W2ext);
    k_node_enc<<<NN / 8, 256, 0, stream>>>(nfeats, emb, encW, encB, projW, projB, h);
    k_edge_t<<<NE / 8, 256, 0, stream>>>(efeats, eencW, eencB, enW1, enB1, t);

    for (int s = 0; s < 3; ++s) {
        hipMemsetAsync(agg, 0, (size_t)NN * 32 * 4, stream);
        if (useQ) {
            k_Q<<<NN / 32, 256, 0, stream>>>(h, W2ext, Q);
            k_msgQ<<<NE / 32, 256, 0, stream>>>(t, src, dst, Q, agg);
        } else {
            k_msgC<<<NE / 32, 256, 0, stream>>>(t, src, dst, h, W2ext, agg);
        }
        k_gru<<<NN / 8, 256, 0, stream>>>(agg, convB, gruWi, gruWh, gruBi, gruBh, h);
    }
    k_dec<<<NN / 8, 256, 0, stream>>>(h, dW1, db1, da1, dW2, db2, da2, dW3, db3, da3, dW4, db4, out);
}